// Round 12
// baseline (1042.738 us; speedup 1.0000x reference)
//
#include <hip/hip_runtime.h>
#include <stdint.h>
#include <stddef.h>

#define DEVINL __device__ __forceinline__

typedef short sv8 __attribute__((ext_vector_type(8)));
typedef unsigned short usv8 __attribute__((ext_vector_type(8)));
typedef unsigned short usv4 __attribute__((ext_vector_type(4)));
typedef float f32x4 __attribute__((ext_vector_type(4)));

constexpr int T_TOK = 4096;   // B*S
constexpr int H_DIM = 2048;
constexpr int I_DIM = 8192;
constexpr int E_NUM = 8;
constexpr int R_LORA = 16;
constexpr float SCALING = 2.0f;
constexpr int NQ = 4;                    // token quarters
constexpr int TQ = T_TOK / NQ;           // 1024 tokens per quarter
constexpr int PQ = TQ * 2;               // 2048 pairs per quarter
constexpr int P_TOT = T_TOK * 2;         // 8192 pairs total

DEVINL float bf2f(unsigned short u) {
  union { uint32_t i; float f; } v; v.i = ((uint32_t)u) << 16; return v.f;
}
DEVINL unsigned short f2bf(float x) {
  union { float f; uint32_t i; } v; v.f = x;
  uint32_t r = v.i + 0x7FFFu + ((v.i >> 16) & 1u);   // RNE
  return (unsigned short)(r >> 16);
}
DEVINL float bflo(uint32_t w) {
  union { uint32_t i; float f; } v; v.i = w << 16; return v.f;
}
DEVINL float bfhi(uint32_t w) {
  union { uint32_t i; float f; } v; v.i = w & 0xFFFF0000u; return v.f;
}

DEVINL f32x4 MFMA_BF16(sv8 a, sv8 b, f32x4 c) {
  return __builtin_amdgcn_mfma_f32_16x16x32_bf16(a, b, c, 0, 0, 0);
}

DEVINL void load16_to_lds(const void* g, void* l) {
  __builtin_amdgcn_global_load_lds(
      (const __attribute__((address_space(1))) uint32_t*)g,
      (__attribute__((address_space(3))) uint32_t*)l, 16, 0, 0);
}

#define BARRIER() __builtin_amdgcn_s_barrier()

// ---------------- elementwise cast f32 -> bf16 (4 elems per thread)
__global__ void cast_f32_to_bf16(const float4* __restrict__ src, usv4* __restrict__ dst) {
  long i = (long)blockIdx.x * blockDim.x + threadIdx.x;
  float4 v = src[i];
  usv4 o;
  o[0] = f2bf(v.x); o[1] = f2bf(v.y); o[2] = f2bf(v.z); o[3] = f2bf(v.w);
  dst[i] = o;
}

// dual-buffer cast: blockIdx.y picks (src0,dst0)/(src1,dst1) — fewer launches
__global__ void cast2_f32_to_bf16(const float4* __restrict__ src0, usv4* __restrict__ dst0,
                                  const float4* __restrict__ src1, usv4* __restrict__ dst1) {
  long i = (long)blockIdx.x * blockDim.x + threadIdx.x;
  const float4* s = blockIdx.y ? src1 : src0;
  usv4* d = blockIdx.y ? dst1 : dst0;
  float4 v = s[i];
  usv4 o;
  o[0] = f2bf(v.x); o[1] = f2bf(v.y); o[2] = f2bf(v.z); o[3] = f2bf(v.w);
  d[i] = o;
}

__global__ void zero_lcnt(int* lcnt) {
  if (threadIdx.x < E_NUM * NQ) lcnt[threadIdx.x] = 0;
}

// ---------------- router: logits, softmax(fp32), top-2 (jax tie-break),
// per-(expert,quarter) pair lists; also emits x cast to bf16
__global__ void router_kernel(const float* __restrict__ x, const float* __restrict__ rW,
                              float* __restrict__ wbuf, int* __restrict__ idxb,
                              float* __restrict__ probs, int* __restrict__ lcnt,
                              int* __restrict__ lists, unsigned short* __restrict__ xf_bf) {
  const int wave = threadIdx.x >> 6, lane = threadIdx.x & 63;
  const int t = blockIdx.x * 4 + wave;
  const float* xr = x + (long)t * H_DIM;
  unsigned short* xbr = xf_bf + (long)t * H_DIM;
  float acc[E_NUM];
#pragma unroll
  for (int e = 0; e < E_NUM; ++e) acc[e] = 0.f;
  for (int h = lane; h < H_DIM; h += 64) {
    float xv = xr[h];
    xbr[h] = f2bf(xv);
#pragma unroll
    for (int e = 0; e < E_NUM; ++e) acc[e] += xv * rW[e * H_DIM + h];
  }
#pragma unroll
  for (int e = 0; e < E_NUM; ++e) {
#pragma unroll
    for (int off = 32; off; off >>= 1) acc[e] += __shfl_xor(acc[e], off);
  }
  if (lane == 0) {
    float mx = acc[0];
#pragma unroll
    for (int e = 1; e < E_NUM; ++e) mx = fmaxf(mx, acc[e]);
    float p[E_NUM];
    float s = 0.f;
#pragma unroll
    for (int e = 0; e < E_NUM; ++e) { p[e] = expf(acc[e] - mx); s += p[e]; }
    float inv = 1.f / s;
#pragma unroll
    for (int e = 0; e < E_NUM; ++e) p[e] *= inv;
    int e1 = 0;
    for (int e = 1; e < E_NUM; ++e) if (p[e] > p[e1]) e1 = e;       // first max
    int e2 = (e1 == 0) ? 1 : 0;
    for (int e = 0; e < E_NUM; ++e) if (e != e1 && p[e] > p[e2]) e2 = e;
    float w1 = p[e1], w2 = p[e2], wsum = w1 + w2;
    wbuf[t * 2 + 0] = w1 / wsum;
    wbuf[t * 2 + 1] = w2 / wsum;
    idxb[t * 2 + 0] = e1;
    idxb[t * 2 + 1] = e2;
#pragma unroll
    for (int e = 0; e < E_NUM; ++e) probs[(long)t * E_NUM + e] = p[e];
    const int q = t / TQ;
    int p1 = atomicAdd(&lcnt[e1 * NQ + q], 1); lists[(e1 * NQ + q) * TQ + p1] = t * 2 + 0;
    int p2 = atomicAdd(&lcnt[e2 * NQ + q], 1); lists[(e2 * NQ + q) * TQ + p2] = t * 2 + 1;
  }
}

// ---------------- aux loss: deterministic single-wave reduction
__global__ void aux_kernel(const float* __restrict__ probs, const int* __restrict__ lcnt,
                           float* __restrict__ aux_out) {
  const int lane = threadIdx.x;
  float s[E_NUM];
#pragma unroll
  for (int e = 0; e < E_NUM; ++e) s[e] = 0.f;
  for (int t = lane; t < T_TOK; t += 64) {
#pragma unroll
    for (int e = 0; e < E_NUM; ++e) s[e] += probs[(long)t * E_NUM + e];
  }
#pragma unroll
  for (int e = 0; e < E_NUM; ++e) {
#pragma unroll
    for (int off = 32; off; off >>= 1) s[e] += __shfl_xor(s[e], off);
  }
  if (lane == 0) {
    float a = 0.f;
#pragma unroll
    for (int e = 0; e < E_NUM; ++e) {
      int cnt = 0;
#pragma unroll
      for (int q = 0; q < NQ; ++q) cnt += lcnt[e * NQ + q];
      a += ((float)cnt / (float)T_TOK) * (s[e] / (float)T_TOK);
    }
    *aux_out = (float)E_NUM * a;
  }
}

// ---------------- (ug,uu) = x @ {gA,uA}.T via MFMA, k-chunked, all quarters
__global__ __launch_bounds__(256)
void lora_a_mfma_kernel(const unsigned short* __restrict__ xf_bf,
                        const unsigned short* __restrict__ gA_bf,
                        const unsigned short* __restrict__ uA_bf,
                        const int* __restrict__ lists, const int* __restrict__ lcnt,
                        float* __restrict__ vg, float* __restrict__ vu) {
  const int q = blockIdx.x / (E_NUM * 16);
  const int rem = blockIdx.x % (E_NUM * 16);
  const int e = rem >> 4;
  const int wave = threadIdx.x >> 6, lane = threadIdx.x & 63;
  const int grp = (rem & 15) * 4 + wave;
  const int npairs = lcnt[e * NQ + q];
  if (grp * 16 >= npairs) return;
  const int* lst = lists + (e * NQ + q) * TQ;
  const int slot = lane & 15;
  int pidx = grp * 16 + slot;
  int pair = lst[(pidx < npairs) ? pidx : grp * 16];   // dup slot0 as pad
  int t = pair >> 1;
  const long kb = (long)blockIdx.y * 1024 + (lane >> 4) * 8;
  const unsigned short* arow = xf_bf + (long)t * H_DIM + kb;
  const unsigned short* bg = gA_bf + ((long)e * R_LORA + slot) * H_DIM + kb;
  const unsigned short* bu = uA_bf + ((long)e * R_LORA + slot) * H_DIM + kb;
  f32x4 ag = {}, au = {};
#pragma unroll 4
  for (int k = 0; k < 1024; k += 32) {
    sv8 a = *(const sv8*)(arow + k);
    ag = MFMA_BF16(a, *(const sv8*)(bg + k), ag);
    au = MFMA_BF16(a, *(const sv8*)(bu + k), au);
  }
  const int orow = (lane >> 4) * 4;
  const long base = (long)blockIdx.y * P_TOT;
#pragma unroll
  for (int rg = 0; rg < 4; ++rg) {
    int pidx2 = grp * 16 + orow + rg;
    if (pidx2 < npairs) {
      int pr = lst[pidx2];
      vg[(base + pr) * R_LORA + slot] = ag[rg];
      vu[(base + pr) * R_LORA + slot] = au[rg];
    }
  }
}

__global__ void reduce_uguu_kernel(const float* __restrict__ vg, const float* __restrict__ vu,
                                   float* __restrict__ ug, float* __restrict__ uu) {
  long i = (long)blockIdx.x * 256 + threadIdx.x;
  ug[i] = vg[i] + vg[(long)P_TOT * R_LORA + i];
  uu[i] = vu[i] + vu[(long)P_TOT * R_LORA + i];
}

// ---------------- 256x256 bf16 GEMM, C = A @ B^T — R12: TWO phases per K-tile
// (R11 halved barriers 8->4/tile, +9%; this halves again 4->2/tile).
// phA: read aLo + ALL B (16 ds_read) -> 32 MFMA; stage Q{A64,A192,B0,B64}.
// phB: read aHi (8 ds_read) -> 32 MFMA; stage Q{B128,B192} + P{A0,A128}(t+2);
//      vmcnt(2) drains exactly t+1's 8 chunks; barrier.
// WAR ledger: Q stages never conflict with P reads; P{A0,A128} stage in phB
// targets rows last read in phA (barrier-separated). Prologue identical to R6.
// F32OUT=false: z selects (B0->Cb0)/(B1->Cb1) dual-B (gemm1).
// F32OUT=true : z selects K-half writing f32 partial Cf+z*cz (gemm2).
template <bool F32OUT>
__global__ __launch_bounds__(512, 2)
void gemm8p_t(const unsigned short* __restrict__ A,
              const unsigned short* __restrict__ B0,
              const unsigned short* __restrict__ B1,
              unsigned short* __restrict__ Cb0,
              unsigned short* __restrict__ Cb1,
              float* __restrict__ Cf,
              int K, int lda, int ldb, int ldc,
              int az_off, int bz_off, long cz_off) {
  extern __shared__ unsigned short lds[];   // [2][2][256][64]
  const int z = blockIdx.z;
  const unsigned short* __restrict__ Ap = A + (long)z * az_off;
  const unsigned short* __restrict__ Bp = (z ? B1 : B0) + (long)z * bz_off;
  const int tid = threadIdx.x;
  const int wave = tid >> 6, lane = tid & 63;
  const int wm = wave >> 2, wn = wave & 3;
  const long m0 = (long)blockIdx.y * 256;
  const long n0 = (long)blockIdx.x * 256;
  const int NT = K >> 6;

  const int lr = lane & 15;
  const int lc = (lane >> 4) * 8;
  const int xm = ((lane & 4) << 3) | ((lane & 2) << 3) | ((lane & 1) << 6);
  const int srow = tid >> 3;
  const int scol = (tid & 7) * 8;
  const int gcol = scol ^ (((tid >> 5) & 1) << 4) ^ (((tid >> 4) & 1) << 3)
                        ^ (((tid >> 3) & 1) << 5);

  f32x4 acc[8][4] = {};
  sv8 aF[4][2], bF[4][2];

  auto ldsAt = [&](int buf, int mat) -> unsigned short* {
    return lds + (((buf << 1) + mat) << 14);
  };
  auto stageA = [&](int buf, int R, long k0) {
    load16_to_lds(Ap + (m0 + R + srow) * (long)lda + k0 + gcol,
                  ldsAt(buf, 0) + ((R + srow) << 6) + scol);
  };
  auto stageB = [&](int buf, int R, long k0) {
    load16_to_lds(Bp + (n0 + R + srow) * (long)ldb + k0 + gcol,
                  ldsAt(buf, 1) + ((R + srow) << 6) + scol);
  };
  auto rdA = [&](int buf, int row16, int ks) -> sv8 {
    int bo = ((((row16 + lr) << 7) + ((ks * 32 + lc) << 1))) ^ xm;
    return *(const sv8*)((const char*)ldsAt(buf, 0) + bo);
  };
  auto rdB = [&](int buf, int row16, int ks) -> sv8 {
    int bo = ((((row16 + lr) << 7) + ((ks * 32 + lc) << 1))) ^ xm;
    return *(const sv8*)((const char*)ldsAt(buf, 1) + bo);
  };

  stageA(0, 0, 0); stageA(0, 64, 0); stageA(0, 128, 0); stageA(0, 192, 0);
  stageB(0, 0, 0); stageB(0, 64, 0); stageB(0, 128, 0); stageB(0, 192, 0);
  if (NT > 1) {
    stageA(1, 0, 64); stageA(1, 128, 64);
    asm volatile("s_waitcnt vmcnt(2)" ::: "memory");
  } else {
    asm volatile("s_waitcnt vmcnt(0)" ::: "memory");
  }
  BARRIER();

  for (int t = 0; t < NT; ++t) {
    const int P = t & 1, Q = P ^ 1;
    const long kQ = ((long)t + 1) << 6;
    const long kP2 = ((long)t + 2) << 6;
    const bool hQ = (t + 1) < NT, hP2 = (t + 2) < NT;

    // ---- phase A: aLo + all B -> 32 MFMA; stage Q A64,A192,B0,B64
#pragma unroll
    for (int mf = 0; mf < 4; ++mf)
#pragma unroll
      for (int ks = 0; ks < 2; ++ks)
        aF[mf][ks] = rdA(P, wm * 128 + mf * 16, ks);
#pragma unroll
    for (int nf = 0; nf < 4; ++nf)
#pragma unroll
      for (int ks = 0; ks < 2; ++ks)
        bF[nf][ks] = rdB(P, wn * 64 + nf * 16, ks);
    if (hQ) { stageA(Q, 64, kQ); stageA(Q, 192, kQ); stageB(Q, 0, kQ); stageB(Q, 64, kQ); }
    __builtin_amdgcn_s_setprio(1);
#pragma unroll
    for (int mf = 0; mf < 4; ++mf)
#pragma unroll
      for (int nf = 0; nf < 4; ++nf)
#pragma unroll
        for (int ks = 0; ks < 2; ++ks)
          acc[mf][nf] = MFMA_BF16(aF[mf][ks], bF[nf][ks], acc[mf][nf]);
    __builtin_amdgcn_s_setprio(0);
    BARRIER();

    // ---- phase B: aHi -> 32 MFMA; stage Q B128,B192 + P A0,A128 (t+2);
    // vmcnt(2) drains t+1's 8 chunks, leaves t+2's A0,A128 in flight.
#pragma unroll
    for (int mf = 0; mf < 4; ++mf)
#pragma unroll
      for (int ks = 0; ks < 2; ++ks)
        aF[mf][ks] = rdA(P, wm * 128 + 64 + mf * 16, ks);
    if (hQ) { stageB(Q, 128, kQ); stageB(Q, 192, kQ); }
    if (hP2) { stageA(P, 0, kP2); stageA(P, 128, kP2); }
    __builtin_amdgcn_s_setprio(1);
#pragma unroll
    for (int mf = 0; mf < 4; ++mf)
#pragma unroll
      for (int nf = 0; nf < 4; ++nf)
#pragma unroll
        for (int ks = 0; ks < 2; ++ks)
          acc[4 + mf][nf] = MFMA_BF16(aF[mf][ks], bF[nf][ks], acc[4 + mf][nf]);
    __builtin_amdgcn_s_setprio(0);
    if (hP2) {
      asm volatile("s_waitcnt vmcnt(2)" ::: "memory");
    } else {
      asm volatile("s_waitcnt vmcnt(0)" ::: "memory");
    }
    BARRIER();
  }

  const int rb = (lane >> 4) * 4, cb = lane & 15;
  if constexpr (F32OUT) {
    float* __restrict__ Cp = Cf + (long)z * cz_off;
#pragma unroll
    for (int mf = 0; mf < 8; ++mf)
#pragma unroll
      for (int nf = 0; nf < 4; ++nf) {
        long col = n0 + wn * 64 + nf * 16 + cb;
#pragma unroll
        for (int r = 0; r < 4; ++r) {
          long row = m0 + wm * 128 + mf * 16 + rb + r;
          Cp[row * ldc + col] = acc[mf][nf][r];
        }
      }
  } else {
    unsigned short* __restrict__ Cp = z ? Cb1 : Cb0;
#pragma unroll
    for (int mf = 0; mf < 8; ++mf)
#pragma unroll
      for (int nf = 0; nf < 4; ++nf) {
        long col = n0 + wn * 64 + nf * 16 + cb;
#pragma unroll
        for (int r = 0; r < 4; ++r) {
          long row = m0 + wm * 128 + mf * 16 + rb + r;
          Cp[row * ldc + col] = f2bf(acc[mf][nf][r]);
        }
      }
  }
}

// ---------------- combine (per token-quarter q), register-resident LoRA-B
__global__ __launch_bounds__(256)
void combine2_kernel(const unsigned short* __restrict__ g_bf,
                     const unsigned short* __restrict__ u_bf,
                     const unsigned short* __restrict__ gBp, const unsigned short* __restrict__ uBp,
                     const float* __restrict__ ug, const float* __restrict__ uu,  // [P_TOT,R]
                     const float* __restrict__ wbuf,
                     const int* __restrict__ lists, const int* __restrict__ lcnt,
                     unsigned short* __restrict__ winter, int q) {
  const int e = blockIdx.y >> 4, chunk = blockIdx.y & 15;
  const int npairs = lcnt[e * NQ + q];
  const int pbase = chunk * 64;
  if (pbase >= npairs) return;
  const int wave = threadIdx.x >> 6, lane = threadIdx.x & 63;
  const long i0 = (long)blockIdx.x * 256 + lane * 4;
  uint32_t gbp[32], ubp[32];
#pragma unroll
  for (int j = 0; j < 4; ++j) {
    const uint4* gp = (const uint4*)(gBp + ((long)e * I_DIM + i0 + j) * R_LORA);
    const uint4* up = (const uint4*)(uBp + ((long)e * I_DIM + i0 + j) * R_LORA);
    uint4 g0 = gp[0], g1 = gp[1], u0 = up[0], u1 = up[1];
    gbp[j * 8 + 0] = g0.x; gbp[j * 8 + 1] = g0.y; gbp[j * 8 + 2] = g0.z; gbp[j * 8 + 3] = g0.w;
    gbp[j * 8 + 4] = g1.x; gbp[j * 8 + 5] = g1.y; gbp[j * 8 + 6] = g1.z; gbp[j * 8 + 7] = g1.w;
    ubp[j * 8 + 0] = u0.x; ubp[j * 8 + 1] = u0.y; ubp[j * 8 + 2] = u0.z; ubp[j * 8 + 3] = u0.w;
    ubp[j * 8 + 4] = u1.x; ubp[j * 8 + 5] = u1.y; ubp[j * 8 + 6] = u1.z; ubp[j * 8 + 7] = u1.w;
  }
  for (int pl = 0; pl < 16; ++pl) {
    int pi = pbase + wave + pl * 4;
    if (pi >= npairs) break;
    int pair = lists[(e * NQ + q) * TQ + pi];
    int t = pair >> 1, plocal = pair - q * PQ;
    float w = wbuf[pair];
    const float2* ug2 = (const float2*)(ug + (long)pair * R_LORA);
    const float2* uu2 = (const float2*)(uu + (long)pair * R_LORA);
    usv4 gv = *(const usv4*)(g_bf + (long)t * I_DIM + i0);
    usv4 uv = *(const usv4*)(u_bf + (long)t * I_DIM + i0);
    float gd[4] = {0.f, 0.f, 0.f, 0.f}, ud[4] = {0.f, 0.f, 0.f, 0.f};
#pragma unroll
    for (int c = 0; c < 8; ++c) {
      float2 a = ug2[c], b = uu2[c];
#pragma unroll
      for (int j = 0; j < 4; ++j) {
        uint32_t gw = gbp[j * 8 + c], uw = ubp[j * 8 + c];
        gd[j] += a.x * bflo(gw) + a.y * bfhi(gw);
        ud[j] += b.x * bflo(uw) + b.y * bfhi(uw);
      }
    }
    usv4 o;
#pragma unroll
    for (int j = 0; j < 4; ++j) {
      float zg = bf2f(gv[j]) + SCALING * gd[j];
      float zu = bf2f(uv[j]) + SCALING * ud[j];
      float sil = zg / (1.f + __expf(-zg));
      o[j] = f2bf(w * sil * zu);
    }
    *(usv4*)(winter + (long)plocal * I_DIM + i0) = o;
  }
}

// ---------------- acc_int = winter0 + winter1 (weights pre-folded), quarter q
__global__ void acc_kernel(const unsigned short* __restrict__ winter,
                           unsigned short* __restrict__ acc_bf, int q) {
  long gid = (long)blockIdx.x * 256 + threadIdx.x;
  int tl = (int)(gid >> 10);
  int ig = (int)(gid & 1023);
  int t = q * TQ + tl;
  usv8 a = *(const usv8*)(winter + ((long)(tl * 2 + 0)) * I_DIM + ig * 8);
  usv8 b = *(const usv8*)(winter + ((long)(tl * 2 + 1)) * I_DIM + ig * 8);
  usv8 o;
#pragma unroll
  for (int j = 0; j < 8; ++j) o[j] = f2bf(bf2f(a[j]) + bf2f(b[j]));
  *(usv8*)(acc_bf + (long)t * I_DIM + ig * 8) = o;
}

// ---------------- v' partials = winter @ down_A.T via MFMA, k-chunked, quarter q
__global__ __launch_bounds__(256)
void lorav_mfma_kernel(const unsigned short* __restrict__ winter,
                       const unsigned short* __restrict__ dA_bf,  // [E,R,I] bf16
                       const int* __restrict__ lists, const int* __restrict__ lcnt,
                       float* __restrict__ vv, int q) {
  const int e = blockIdx.x >> 4;
  const int wave = threadIdx.x >> 6, lane = threadIdx.x & 63;
  const int grp = (blockIdx.x & 15) * 4 + wave;
  const int npairs = lcnt[e * NQ + q];
  if (grp * 16 >= npairs) return;
  const int* lst = lists + (e * NQ + q) * TQ;
  const int slot = lane & 15;
  int pidx = grp * 16 + slot;
  int pair = lst[(pidx < npairs) ? pidx : grp * 16];   // dup slot0 as pad
  int plocal = pair - q * PQ;
  const long kb = (long)blockIdx.y * 1024 + (lane >> 4) * 8;
  const unsigned short* arow = winter + (long)plocal * I_DIM + kb;
  const unsigned short* brow = dA_bf + ((long)e * R_LORA + slot) * I_DIM + kb;
  f32x4 acc = {};
#pragma unroll 4
  for (int k = 0; k < 1024; k += 32)
    acc = MFMA_BF16(*(const sv8*)(arow + k), *(const sv8*)(brow + k), acc);
  const int orow = (lane >> 4) * 4;
  const long base = (long)blockIdx.y * P_TOT;
#pragma unroll
  for (int rg = 0; rg < 4; ++rg) {
    int pidx2 = grp * 16 + orow + rg;
    if (pidx2 < npairs) {
      int pr = lst[pidx2];
      vv[(base + pr) * R_LORA + slot] = acc[rg];
    }
  }
}

__global__ void reduce_v_kernel(const float* __restrict__ vv, float* __restrict__ vbuf) {
  long i = (long)blockIdx.x * 256 + threadIdx.x;
  float s = 0.f;
#pragma unroll
  for (int kc = 0; kc < 8; ++kc) s += vv[(long)kc * P_TOT * R_LORA + i];
  vbuf[i] = s;
}

// ---------------- fused epilogue: out = SC*(v'0@dB[e0].T + v'1@dB[e1].T) + p0 + p1
__global__ void ddmerge_kernel(const float* __restrict__ vbuf, const int* __restrict__ idxb,
                               const float* __restrict__ dB,   // [E,H,R] f32
                               const float* __restrict__ p0, const float* __restrict__ p1,
                               float* __restrict__ out) {
  const int t = blockIdx.y;
  const int h = blockIdx.x * 256 + threadIdx.x;
  const int e0 = idxb[t * 2 + 0], e1 = idxb[t * 2 + 1];
  const float4* v0p = (const float4*)(vbuf + (long)(t * 2 + 0) * R_LORA);
  const float4* v1p = (const float4*)(vbuf + (long)(t * 2 + 1) * R_LORA);
  const float4* b0 = (const float4*)(dB + ((long)e0 * H_DIM + h) * R_LORA);
  const float4* b1 = (const float4*)(dB + ((long)e1 * H_DIM + h) * R_LORA);
  float dd = 0.f;
#pragma unroll
  for (int qq = 0; qq < 4; ++qq) {
    float4 v0 = v0p[qq], x0 = b0[qq];
    float4 v1 = v1p[qq], x1 = b1[qq];
    dd += v0.x * x0.x + v0.y * x0.y + v0.z * x0.z + v0.w * x0.w;
    dd += v1.x * x1.x + v1.y * x1.y + v1.z * x1.z + v1.w * x1.w;
  }
  long i = (long)t * H_DIM + h;
  out[i] = SCALING * dd + p0[i] + p1[i];
}

// =======================================================================
extern "C" void kernel_launch(void* const* d_in, const int* in_sizes, int n_in,
                              void* d_out, int out_size, void* d_ws, size_t ws_size,
                              hipStream_t stream) {
  (void)in_sizes; (void)n_in; (void)out_size;
  const float* x        = (const float*)d_in[0];
  const float* gate_W   = (const float*)d_in[1];
  const float* up_W     = (const float*)d_in[2];
  const float* down_W   = (const float*)d_in[3];
  const float* router_W = (const float*)d_in[4];
  const float* gate_A   = (const float*)d_in[5];
  const float* gate_B   = (const float*)d_in[6];
  const float* up_A     = (const float*)d_in[7];
  const float* up_B     = (const float*)d_in[8];
  const float* down_A   = (const float*)d_in[9];
  const float* down_B   = (const float*)d_in[10];
  float* out = (float*)d_out;

  char* ws = (char*)d_ws;
  size_t off = 0;
  auto take = [&](size_t bytes) -> char* {
    char* p = ws + off;
    off += (bytes + 255) & ~(size_t)255;
    return p;
  };
  unsigned short* xf_bf  = (unsigned short*)take((size_t)T_TOK * H_DIM * 2);          // 16MB; -> vv/gB_bf/uB_bf after gemm1
  unsigned short* gW_bf  = (unsigned short*)take((size_t)I_DIM * H_DIM * 2);          // 32MB; -> dW_bf after gemm1
  unsigned short* uW_bf  = (unsigned short*)take((size_t)I_DIM * H_DIM * 2);          // 32MB
  unsigned short* dA_bf  = (unsigned short*)take((size_t)E_NUM * R_LORA * I_DIM * 2); // 2MB
  unsigned short* g_bf   = (unsigned short*)take((size_t)T_TOK * I_DIM * 2);          // 64MB; -> acc_bf per quarter
  unsigned short* u_bf   = (unsigned short*)take((size_t)T_TOK * I_DIM * 2);          // 64MB; -> f32 partials for gemm2
  unsigned short* winterQ= (unsigned short*)take((size_t)PQ * I_DIM * 2);             // 32MB; hosts vg/vu/gA_bf/uA_bf pre-combine
  float* wbuf  = (float*)take((size_t)P_TOT * 4);
  int*   idxb  = (int*)take((size_t)P_TOT * 4);
  float* ug    = (float*)take((size_t)P_TOT * R_LORA * 4);
  float* uu    = (float*)take((size_t)P_TOT * R_LORA * 4);
  float* vbuf  = (float*)take((size_t)P_TOT * R_LORA * 4);
  float* probs = (float*)take((size_t)T_TOK * E_NUM * 4);
  int*   lcnt  = (int*)take((size_t)E_NUM * NQ * 4);
  int*   lists = (int*)take((size_t)E_NUM * NQ * TQ * 4);

  // Aliases (stream-ordered reuse of dead buffers):
  unsigned short* dW_bf  = gW_bf;           // cast after gemm1 consumed gW_bf
  unsigned short* acc_bf = g_bf;            // acc(q) overwrites rows combine(q) read
  float* vg = (float*)winterQ;
  float* vu = (float*)(winterQ + (size_t)1 * 1024 * 1024 / 2);
  unsigned short* gA_bf = winterQ + (size_t)2 * 1024 * 1024 / 2;
  unsigned short* uA_bf = winterQ + (size_t)5 * 512 * 1024 / 2;
  // xf region (16MB) after gemm1: vv [0,4MB), gB_bf [4,8MB), uB_bf [8,12MB)
  float* vv = (float*)xf_bf;
  unsigned short* gB_bf = (unsigned short*)((char*)xf_bf + ((size_t)4 << 20));
  unsigned short* uB_bf = (unsigned short*)((char*)xf_bf + ((size_t)8 << 20));
  float* pbuf = (float*)u_bf;               // 64MB = 2 x f32 partial of gemm2 (u_bf dead)

  if (ws_size < off) return;  // clean absmax-fail signals ws too small

  // 1. stats + router (emits xf_bf) + aux
  zero_lcnt<<<1, 64, 0, stream>>>(lcnt);
  router_kernel<<<T_TOK / 4, 256, 0, stream>>>(x, router_W, wbuf, idxb, probs, lcnt, lists, xf_bf);
  aux_kernel<<<1, 64, 0, stream>>>(probs, lcnt, out + (size_t)T_TOK * H_DIM);

  // 2. LoRA-A casts (fused pair) + pair-GEMM (MFMA, k-chunked) + reduce
  cast2_f32_to_bf16<<<dim3((E_NUM * R_LORA * H_DIM / 4) / 256, 2), 256, 0, stream>>>(
      (const float4*)gate_A, (usv4*)gA_bf, (const float4*)up_A, (usv4*)uA_bf);
  lora_a_mfma_kernel<<<dim3(NQ * E_NUM * 16, 2), 256, 0, stream>>>(xf_bf, gA_bf, uA_bf, lists, lcnt, vg, vu);
  reduce_uguu_kernel<<<(P_TOT * R_LORA) / 256, 256, 0, stream>>>(vg, vu, ug, uu);

  // 3. big-weight casts (gate_W + up_W fused)
  cast2_f32_to_bf16<<<dim3((I_DIM * H_DIM / 4) / 256, 2), 256, 0, stream>>>(
      (const float4*)gate_W, (usv4*)gW_bf, (const float4*)up_W, (usv4*)uW_bf);
  cast_f32_to_bf16<<<(E_NUM * R_LORA * I_DIM / 4) / 256, 256, 0, stream>>>((const float4*)down_A, (usv4*)dA_bf);

  // 4. fused gate/up base GEMM — 256² 2-phase, z picks (gate, up)
  hipFuncSetAttribute(reinterpret_cast<const void*>(&gemm8p_t<false>),
                      hipFuncAttributeMaxDynamicSharedMemorySize, 131072);
  hipFuncSetAttribute(reinterpret_cast<const void*>(&gemm8p_t<true>),
                      hipFuncAttributeMaxDynamicSharedMemorySize, 131072);
  gemm8p_t<false><<<dim3(I_DIM / 256, T_TOK / 256, 2), 512, 131072, stream>>>(
      xf_bf, gW_bf, uW_bf, g_bf, u_bf, nullptr,
      H_DIM, H_DIM, H_DIM, I_DIM, 0, 0, 0);

  // 5. dead-buffer casts: down_W -> gW region; gate_B/up_B bf16-pack -> xf region
  cast_f32_to_bf16<<<(H_DIM * I_DIM / 4) / 256, 256, 0, stream>>>((const float4*)down_W, (usv4*)dW_bf);
  cast2_f32_to_bf16<<<dim3((E_NUM * I_DIM * R_LORA / 4) / 256, 2), 256, 0, stream>>>(
      (const float4*)gate_B, (usv4*)gB_bf, (const float4*)up_B, (usv4*)uB_bf);

  // 6. per token-quarter: SwiGLU+LoRA-B (weighted) -> acc -> k-chunked lora_v
  for (int q = 0; q < NQ; ++q) {
    combine2_kernel<<<dim3(I_DIM / 256, E_NUM * 16), 256, 0, stream>>>(
        g_bf, u_bf, gB_bf, uB_bf, ug, uu, wbuf, lists, lcnt, winterQ, q);
    acc_kernel<<<(TQ * (I_DIM / 8)) / 256, 256, 0, stream>>>(winterQ, acc_bf, q);
    lorav_mfma_kernel<<<dim3(E_NUM * 16, 8), 256, 0, stream>>>(winterQ, dA_bf, lists, lcnt, vv, q);
  }
  reduce_v_kernel<<<(P_TOT * R_LORA) / 256, 256, 0, stream>>>(vv, vbuf);

  // 7. down GEMM — 2-phase split-K (z = K-half), f32 partials
  gemm8p_t<true><<<dim3(H_DIM / 256, T_TOK / 256, 2), 512, 131072, stream>>>(
      acc_bf, dW_bf, dW_bf, nullptr, nullptr, pbuf,
      I_DIM / 2, I_DIM, I_DIM, H_DIM, I_DIM / 2, I_DIM / 2, (long)T_TOK * H_DIM);

  // 8. fused epilogue: out = SC*dd + p0 + p1
  ddmerge_kernel<<<dim3(H_DIM / 256, T_TOK), 256, 0, stream>>>(
      vbuf, idxb, down_B, (const float*)pbuf,
      (const float*)(pbuf + (size_t)T_TOK * H_DIM), out);
}

// Round 13
// 1039.307 us; speedup vs baseline: 1.0033x; 1.0033x over previous
//
#include <hip/hip_runtime.h>
#include <stdint.h>
#include <stddef.h>

#define DEVINL __device__ __forceinline__

typedef short sv8 __attribute__((ext_vector_type(8)));
typedef unsigned short usv8 __attribute__((ext_vector_type(8)));
typedef unsigned short usv4 __attribute__((ext_vector_type(4)));
typedef float f32x4 __attribute__((ext_vector_type(4)));

constexpr int T_TOK = 4096;   // B*S
constexpr int H_DIM = 2048;
constexpr int I_DIM = 8192;
constexpr int E_NUM = 8;
constexpr int R_LORA = 16;
constexpr float SCALING = 2.0f;
constexpr int NQ = 4;                    // token quarters
constexpr int TQ = T_TOK / NQ;           // 1024 tokens per quarter
constexpr int PQ = TQ * 2;               // 2048 pairs per quarter
constexpr int P_TOT = T_TOK * 2;         // 8192 pairs total

DEVINL float bf2f(unsigned short u) {
  union { uint32_t i; float f; } v; v.i = ((uint32_t)u) << 16; return v.f;
}
DEVINL unsigned short f2bf(float x) {
  union { float f; uint32_t i; } v; v.f = x;
  uint32_t r = v.i + 0x7FFFu + ((v.i >> 16) & 1u);   // RNE
  return (unsigned short)(r >> 16);
}
DEVINL float bflo(uint32_t w) {
  union { uint32_t i; float f; } v; v.i = w << 16; return v.f;
}
DEVINL float bfhi(uint32_t w) {
  union { uint32_t i; float f; } v; v.i = w & 0xFFFF0000u; return v.f;
}

DEVINL f32x4 MFMA_BF16(sv8 a, sv8 b, f32x4 c) {
  return __builtin_amdgcn_mfma_f32_16x16x32_bf16(a, b, c, 0, 0, 0);
}

DEVINL void load16_to_lds(const void* g, void* l) {
  __builtin_amdgcn_global_load_lds(
      (const __attribute__((address_space(1))) uint32_t*)g,
      (__attribute__((address_space(3))) uint32_t*)l, 16, 0, 0);
}

#define BARRIER() __builtin_amdgcn_s_barrier()

// ---------------- elementwise cast f32 -> bf16 (4 elems per thread)
__global__ void cast_f32_to_bf16(const float4* __restrict__ src, usv4* __restrict__ dst) {
  long i = (long)blockIdx.x * blockDim.x + threadIdx.x;
  float4 v = src[i];
  usv4 o;
  o[0] = f2bf(v.x); o[1] = f2bf(v.y); o[2] = f2bf(v.z); o[3] = f2bf(v.w);
  dst[i] = o;
}

// dual-buffer cast: blockIdx.y picks (src0,dst0)/(src1,dst1)
__global__ void cast2_f32_to_bf16(const float4* __restrict__ src0, usv4* __restrict__ dst0,
                                  const float4* __restrict__ src1, usv4* __restrict__ dst1) {
  long i = (long)blockIdx.x * blockDim.x + threadIdx.x;
  const float4* s = blockIdx.y ? src1 : src0;
  usv4* d = blockIdx.y ? dst1 : dst0;
  float4 v = s[i];
  usv4 o;
  o[0] = f2bf(v.x); o[1] = f2bf(v.y); o[2] = f2bf(v.z); o[3] = f2bf(v.w);
  d[i] = o;
}

__global__ void zero_lcnt(int* lcnt) {
  if (threadIdx.x < E_NUM * NQ) lcnt[threadIdx.x] = 0;
}

// ---------------- router: logits, softmax(fp32), top-2 (jax tie-break),
// per-(expert,quarter) pair lists; also emits x cast to bf16
__global__ void router_kernel(const float* __restrict__ x, const float* __restrict__ rW,
                              float* __restrict__ wbuf, int* __restrict__ idxb,
                              float* __restrict__ probs, int* __restrict__ lcnt,
                              int* __restrict__ lists, unsigned short* __restrict__ xf_bf) {
  const int wave = threadIdx.x >> 6, lane = threadIdx.x & 63;
  const int t = blockIdx.x * 4 + wave;
  const float* xr = x + (long)t * H_DIM;
  unsigned short* xbr = xf_bf + (long)t * H_DIM;
  float acc[E_NUM];
#pragma unroll
  for (int e = 0; e < E_NUM; ++e) acc[e] = 0.f;
  for (int h = lane; h < H_DIM; h += 64) {
    float xv = xr[h];
    xbr[h] = f2bf(xv);
#pragma unroll
    for (int e = 0; e < E_NUM; ++e) acc[e] += xv * rW[e * H_DIM + h];
  }
#pragma unroll
  for (int e = 0; e < E_NUM; ++e) {
#pragma unroll
    for (int off = 32; off; off >>= 1) acc[e] += __shfl_xor(acc[e], off);
  }
  if (lane == 0) {
    float mx = acc[0];
#pragma unroll
    for (int e = 1; e < E_NUM; ++e) mx = fmaxf(mx, acc[e]);
    float p[E_NUM];
    float s = 0.f;
#pragma unroll
    for (int e = 0; e < E_NUM; ++e) { p[e] = expf(acc[e] - mx); s += p[e]; }
    float inv = 1.f / s;
#pragma unroll
    for (int e = 0; e < E_NUM; ++e) p[e] *= inv;
    int e1 = 0;
    for (int e = 1; e < E_NUM; ++e) if (p[e] > p[e1]) e1 = e;       // first max
    int e2 = (e1 == 0) ? 1 : 0;
    for (int e = 0; e < E_NUM; ++e) if (e != e1 && p[e] > p[e2]) e2 = e;
    float w1 = p[e1], w2 = p[e2], wsum = w1 + w2;
    wbuf[t * 2 + 0] = w1 / wsum;
    wbuf[t * 2 + 1] = w2 / wsum;
    idxb[t * 2 + 0] = e1;
    idxb[t * 2 + 1] = e2;
#pragma unroll
    for (int e = 0; e < E_NUM; ++e) probs[(long)t * E_NUM + e] = p[e];
    const int q = t / TQ;
    int p1 = atomicAdd(&lcnt[e1 * NQ + q], 1); lists[(e1 * NQ + q) * TQ + p1] = t * 2 + 0;
    int p2 = atomicAdd(&lcnt[e2 * NQ + q], 1); lists[(e2 * NQ + q) * TQ + p2] = t * 2 + 1;
  }
}

// ---------------- aux loss: deterministic single-wave reduction
__global__ void aux_kernel(const float* __restrict__ probs, const int* __restrict__ lcnt,
                           float* __restrict__ aux_out) {
  const int lane = threadIdx.x;
  float s[E_NUM];
#pragma unroll
  for (int e = 0; e < E_NUM; ++e) s[e] = 0.f;
  for (int t = lane; t < T_TOK; t += 64) {
#pragma unroll
    for (int e = 0; e < E_NUM; ++e) s[e] += probs[(long)t * E_NUM + e];
  }
#pragma unroll
  for (int e = 0; e < E_NUM; ++e) {
#pragma unroll
    for (int off = 32; off; off >>= 1) s[e] += __shfl_xor(s[e], off);
  }
  if (lane == 0) {
    float a = 0.f;
#pragma unroll
    for (int e = 0; e < E_NUM; ++e) {
      int cnt = 0;
#pragma unroll
      for (int q = 0; q < NQ; ++q) cnt += lcnt[e * NQ + q];
      a += ((float)cnt / (float)T_TOK) * (s[e] / (float)T_TOK);
    }
    *aux_out = (float)E_NUM * a;
  }
}

// ---------------- (ug,uu) = x @ {gA,uA}.T via MFMA, k-chunked, all quarters
__global__ __launch_bounds__(256)
void lora_a_mfma_kernel(const unsigned short* __restrict__ xf_bf,
                        const unsigned short* __restrict__ gA_bf,
                        const unsigned short* __restrict__ uA_bf,
                        const int* __restrict__ lists, const int* __restrict__ lcnt,
                        float* __restrict__ vg, float* __restrict__ vu) {
  const int q = blockIdx.x / (E_NUM * 16);
  const int rem = blockIdx.x % (E_NUM * 16);
  const int e = rem >> 4;
  const int wave = threadIdx.x >> 6, lane = threadIdx.x & 63;
  const int grp = (rem & 15) * 4 + wave;
  const int npairs = lcnt[e * NQ + q];
  if (grp * 16 >= npairs) return;
  const int* lst = lists + (e * NQ + q) * TQ;
  const int slot = lane & 15;
  int pidx = grp * 16 + slot;
  int pair = lst[(pidx < npairs) ? pidx : grp * 16];   // dup slot0 as pad
  int t = pair >> 1;
  const long kb = (long)blockIdx.y * 1024 + (lane >> 4) * 8;
  const unsigned short* arow = xf_bf + (long)t * H_DIM + kb;
  const unsigned short* bg = gA_bf + ((long)e * R_LORA + slot) * H_DIM + kb;
  const unsigned short* bu = uA_bf + ((long)e * R_LORA + slot) * H_DIM + kb;
  f32x4 ag = {}, au = {};
#pragma unroll 4
  for (int k = 0; k < 1024; k += 32) {
    sv8 a = *(const sv8*)(arow + k);
    ag = MFMA_BF16(a, *(const sv8*)(bg + k), ag);
    au = MFMA_BF16(a, *(const sv8*)(bu + k), au);
  }
  const int orow = (lane >> 4) * 4;
  const long base = (long)blockIdx.y * P_TOT;
#pragma unroll
  for (int rg = 0; rg < 4; ++rg) {
    int pidx2 = grp * 16 + orow + rg;
    if (pidx2 < npairs) {
      int pr = lst[pidx2];
      vg[(base + pr) * R_LORA + slot] = ag[rg];
      vu[(base + pr) * R_LORA + slot] = au[rg];
    }
  }
}

__global__ void reduce_uguu_kernel(const float* __restrict__ vg, const float* __restrict__ vu,
                                   float* __restrict__ ug, float* __restrict__ uu) {
  long i = (long)blockIdx.x * 256 + threadIdx.x;
  ug[i] = vg[i] + vg[(long)P_TOT * R_LORA + i];
  uu[i] = vu[i] + vu[(long)P_TOT * R_LORA + i];
}

// ---------------- 256x256 bf16 GEMM, C = A @ B^T — 2 phases/K-tile.
// R13: staging reshuffled for latency cover — phA stages ALL 6 remaining t+1
// chunks (A64,A192,B0..B192); phB stages only t+2's A0,A128. vmcnt(2) at phB
// still drains exactly t+1's 8 chunks, but the youngest drained chunk now has
// a full phase (~460+cyc) of MFMA/read cover instead of ~160cyc.
// WAR ledger: Q untouched by tile-t reads; P{A0,A128} staged in phB were read
// in phA (barrier-separated); prologue already matches this steady state.
template <bool F32OUT>
__global__ __launch_bounds__(512, 2)
void gemm8p_t(const unsigned short* __restrict__ A,
              const unsigned short* __restrict__ B0,
              const unsigned short* __restrict__ B1,
              unsigned short* __restrict__ Cb0,
              unsigned short* __restrict__ Cb1,
              float* __restrict__ Cf,
              int K, int lda, int ldb, int ldc,
              int az_off, int bz_off, long cz_off) {
  extern __shared__ unsigned short lds[];   // [2][2][256][64]
  const int z = blockIdx.z;
  const unsigned short* __restrict__ Ap = A + (long)z * az_off;
  const unsigned short* __restrict__ Bp = (z ? B1 : B0) + (long)z * bz_off;
  const int tid = threadIdx.x;
  const int wave = tid >> 6, lane = tid & 63;
  const int wm = wave >> 2, wn = wave & 3;
  const long m0 = (long)blockIdx.y * 256;
  const long n0 = (long)blockIdx.x * 256;
  const int NT = K >> 6;

  const int lr = lane & 15;
  const int lc = (lane >> 4) * 8;
  const int xm = ((lane & 4) << 3) | ((lane & 2) << 3) | ((lane & 1) << 6);
  const int srow = tid >> 3;
  const int scol = (tid & 7) * 8;
  const int gcol = scol ^ (((tid >> 5) & 1) << 4) ^ (((tid >> 4) & 1) << 3)
                        ^ (((tid >> 3) & 1) << 5);

  f32x4 acc[8][4] = {};
  sv8 aF[4][2], bF[4][2];

  auto ldsAt = [&](int buf, int mat) -> unsigned short* {
    return lds + (((buf << 1) + mat) << 14);
  };
  auto stageA = [&](int buf, int R, long k0) {
    load16_to_lds(Ap + (m0 + R + srow) * (long)lda + k0 + gcol,
                  ldsAt(buf, 0) + ((R + srow) << 6) + scol);
  };
  auto stageB = [&](int buf, int R, long k0) {
    load16_to_lds(Bp + (n0 + R + srow) * (long)ldb + k0 + gcol,
                  ldsAt(buf, 1) + ((R + srow) << 6) + scol);
  };
  auto rdA = [&](int buf, int row16, int ks) -> sv8 {
    int bo = ((((row16 + lr) << 7) + ((ks * 32 + lc) << 1))) ^ xm;
    return *(const sv8*)((const char*)ldsAt(buf, 0) + bo);
  };
  auto rdB = [&](int buf, int row16, int ks) -> sv8 {
    int bo = ((((row16 + lr) << 7) + ((ks * 32 + lc) << 1))) ^ xm;
    return *(const sv8*)((const char*)ldsAt(buf, 1) + bo);
  };

  stageA(0, 0, 0); stageA(0, 64, 0); stageA(0, 128, 0); stageA(0, 192, 0);
  stageB(0, 0, 0); stageB(0, 64, 0); stageB(0, 128, 0); stageB(0, 192, 0);
  if (NT > 1) {
    stageA(1, 0, 64); stageA(1, 128, 64);
    asm volatile("s_waitcnt vmcnt(2)" ::: "memory");
  } else {
    asm volatile("s_waitcnt vmcnt(0)" ::: "memory");
  }
  BARRIER();

  for (int t = 0; t < NT; ++t) {
    const int P = t & 1, Q = P ^ 1;
    const long kQ = ((long)t + 1) << 6;
    const long kP2 = ((long)t + 2) << 6;
    const bool hQ = (t + 1) < NT, hP2 = (t + 2) < NT;

    // ---- phase A: aLo + all B -> 32 MFMA; stage ALL 6 remaining t+1 chunks -> Q
#pragma unroll
    for (int mf = 0; mf < 4; ++mf)
#pragma unroll
      for (int ks = 0; ks < 2; ++ks)
        aF[mf][ks] = rdA(P, wm * 128 + mf * 16, ks);
#pragma unroll
    for (int nf = 0; nf < 4; ++nf)
#pragma unroll
      for (int ks = 0; ks < 2; ++ks)
        bF[nf][ks] = rdB(P, wn * 64 + nf * 16, ks);
    if (hQ) {
      stageA(Q, 64, kQ); stageA(Q, 192, kQ);
      stageB(Q, 0, kQ); stageB(Q, 64, kQ); stageB(Q, 128, kQ); stageB(Q, 192, kQ);
    }
    __builtin_amdgcn_s_setprio(1);
#pragma unroll
    for (int mf = 0; mf < 4; ++mf)
#pragma unroll
      for (int nf = 0; nf < 4; ++nf)
#pragma unroll
        for (int ks = 0; ks < 2; ++ks)
          acc[mf][nf] = MFMA_BF16(aF[mf][ks], bF[nf][ks], acc[mf][nf]);
    __builtin_amdgcn_s_setprio(0);
    BARRIER();

    // ---- phase B: aHi -> 32 MFMA; stage t+2's A0,A128 -> P; vmcnt(2); barrier
#pragma unroll
    for (int mf = 0; mf < 4; ++mf)
#pragma unroll
      for (int ks = 0; ks < 2; ++ks)
        aF[mf][ks] = rdA(P, wm * 128 + 64 + mf * 16, ks);
    if (hP2) { stageA(P, 0, kP2); stageA(P, 128, kP2); }
    __builtin_amdgcn_s_setprio(1);
#pragma unroll
    for (int mf = 0; mf < 4; ++mf)
#pragma unroll
      for (int nf = 0; nf < 4; ++nf)
#pragma unroll
        for (int ks = 0; ks < 2; ++ks)
          acc[4 + mf][nf] = MFMA_BF16(aF[mf][ks], bF[nf][ks], acc[4 + mf][nf]);
    __builtin_amdgcn_s_setprio(0);
    if (hP2) {
      asm volatile("s_waitcnt vmcnt(2)" ::: "memory");
    } else {
      asm volatile("s_waitcnt vmcnt(0)" ::: "memory");
    }
    BARRIER();
  }

  const int rb = (lane >> 4) * 4, cb = lane & 15;
  if constexpr (F32OUT) {
    float* __restrict__ Cp = Cf + (long)z * cz_off;
#pragma unroll
    for (int mf = 0; mf < 8; ++mf)
#pragma unroll
      for (int nf = 0; nf < 4; ++nf) {
        long col = n0 + wn * 64 + nf * 16 + cb;
#pragma unroll
        for (int r = 0; r < 4; ++r) {
          long row = m0 + wm * 128 + mf * 16 + rb + r;
          Cp[row * ldc + col] = acc[mf][nf][r];
        }
      }
  } else {
    unsigned short* __restrict__ Cp = z ? Cb1 : Cb0;
#pragma unroll
    for (int mf = 0; mf < 8; ++mf)
#pragma unroll
      for (int nf = 0; nf < 4; ++nf) {
        long col = n0 + wn * 64 + nf * 16 + cb;
#pragma unroll
        for (int r = 0; r < 4; ++r) {
          long row = m0 + wm * 128 + mf * 16 + rb + r;
          Cp[row * ldc + col] = f2bf(acc[mf][nf][r]);
        }
      }
  }
}

// ---------------- combine (quarter q = q0 + blockIdx.z), register-resident LoRA-B
__global__ __launch_bounds__(256)
void combine2_kernel(const unsigned short* __restrict__ g_bf,
                     const unsigned short* __restrict__ u_bf,
                     const unsigned short* __restrict__ gBp, const unsigned short* __restrict__ uBp,
                     const float* __restrict__ ug, const float* __restrict__ uu,  // [P_TOT,R]
                     const float* __restrict__ wbuf,
                     const int* __restrict__ lists, const int* __restrict__ lcnt,
                     unsigned short* __restrict__ winter, int q0) {
  const int zq = blockIdx.z;
  const int q = q0 + zq;
  unsigned short* __restrict__ wint = winter + (size_t)zq * PQ * I_DIM;
  const int e = blockIdx.y >> 4, chunk = blockIdx.y & 15;
  const int npairs = lcnt[e * NQ + q];
  const int pbase = chunk * 64;
  if (pbase >= npairs) return;
  const int wave = threadIdx.x >> 6, lane = threadIdx.x & 63;
  const long i0 = (long)blockIdx.x * 256 + lane * 4;
  uint32_t gbp[32], ubp[32];
#pragma unroll
  for (int j = 0; j < 4; ++j) {
    const uint4* gp = (const uint4*)(gBp + ((long)e * I_DIM + i0 + j) * R_LORA);
    const uint4* up = (const uint4*)(uBp + ((long)e * I_DIM + i0 + j) * R_LORA);
    uint4 g0 = gp[0], g1 = gp[1], u0 = up[0], u1 = up[1];
    gbp[j * 8 + 0] = g0.x; gbp[j * 8 + 1] = g0.y; gbp[j * 8 + 2] = g0.z; gbp[j * 8 + 3] = g0.w;
    gbp[j * 8 + 4] = g1.x; gbp[j * 8 + 5] = g1.y; gbp[j * 8 + 6] = g1.z; gbp[j * 8 + 7] = g1.w;
    ubp[j * 8 + 0] = u0.x; ubp[j * 8 + 1] = u0.y; ubp[j * 8 + 2] = u0.z; ubp[j * 8 + 3] = u0.w;
    ubp[j * 8 + 4] = u1.x; ubp[j * 8 + 5] = u1.y; ubp[j * 8 + 6] = u1.z; ubp[j * 8 + 7] = u1.w;
  }
  for (int pl = 0; pl < 16; ++pl) {
    int pi = pbase + wave + pl * 4;
    if (pi >= npairs) break;
    int pair = lists[(e * NQ + q) * TQ + pi];
    int t = pair >> 1, plocal = pair - q * PQ;
    float w = wbuf[pair];
    const float2* ug2 = (const float2*)(ug + (long)pair * R_LORA);
    const float2* uu2 = (const float2*)(uu + (long)pair * R_LORA);
    usv4 gv = *(const usv4*)(g_bf + (long)t * I_DIM + i0);
    usv4 uv = *(const usv4*)(u_bf + (long)t * I_DIM + i0);
    float gd[4] = {0.f, 0.f, 0.f, 0.f}, ud[4] = {0.f, 0.f, 0.f, 0.f};
#pragma unroll
    for (int c = 0; c < 8; ++c) {
      float2 a = ug2[c], b = uu2[c];
#pragma unroll
      for (int j = 0; j < 4; ++j) {
        uint32_t gw = gbp[j * 8 + c], uw = ubp[j * 8 + c];
        gd[j] += a.x * bflo(gw) + a.y * bfhi(gw);
        ud[j] += b.x * bflo(uw) + b.y * bfhi(uw);
      }
    }
    usv4 o;
#pragma unroll
    for (int j = 0; j < 4; ++j) {
      float zg = bf2f(gv[j]) + SCALING * gd[j];
      float zu = bf2f(uv[j]) + SCALING * ud[j];
      float sil = zg / (1.f + __expf(-zg));
      o[j] = f2bf(w * sil * zu);
    }
    *(usv4*)(wint + (long)plocal * I_DIM + i0) = o;
  }
}

// ---------------- acc_int = winter0 + winter1, quarter q = q0 + blockIdx.z
__global__ void acc_kernel(const unsigned short* __restrict__ winter,
                           unsigned short* __restrict__ acc_bf, int q0) {
  const int zq = blockIdx.z;
  const unsigned short* __restrict__ wint = winter + (size_t)zq * PQ * I_DIM;
  long gid = (long)blockIdx.x * 256 + threadIdx.x;
  int tl = (int)(gid >> 10);
  int ig = (int)(gid & 1023);
  int t = (q0 + zq) * TQ + tl;
  usv8 a = *(const usv8*)(wint + ((long)(tl * 2 + 0)) * I_DIM + ig * 8);
  usv8 b = *(const usv8*)(wint + ((long)(tl * 2 + 1)) * I_DIM + ig * 8);
  usv8 o;
#pragma unroll
  for (int j = 0; j < 8; ++j) o[j] = f2bf(bf2f(a[j]) + bf2f(b[j]));
  *(usv8*)(acc_bf + (long)t * I_DIM + ig * 8) = o;
}

// ---------------- v' partials = winter @ down_A.T via MFMA, k-chunked,
// quarter q = q0 + blockIdx.z
__global__ __launch_bounds__(256)
void lorav_mfma_kernel(const unsigned short* __restrict__ winter,
                       const unsigned short* __restrict__ dA_bf,  // [E,R,I] bf16
                       const int* __restrict__ lists, const int* __restrict__ lcnt,
                       float* __restrict__ vv, int q0) {
  const int zq = blockIdx.z;
  const int q = q0 + zq;
  const unsigned short* __restrict__ wint = winter + (size_t)zq * PQ * I_DIM;
  const int e = blockIdx.x >> 4;
  const int wave = threadIdx.x >> 6, lane = threadIdx.x & 63;
  const int grp = (blockIdx.x & 15) * 4 + wave;
  const int npairs = lcnt[e * NQ + q];
  if (grp * 16 >= npairs) return;
  const int* lst = lists + (e * NQ + q) * TQ;
  const int slot = lane & 15;
  int pidx = grp * 16 + slot;
  int pair = lst[(pidx < npairs) ? pidx : grp * 16];   // dup slot0 as pad
  int plocal = pair - q * PQ;
  const long kb = (long)blockIdx.y * 1024 + (lane >> 4) * 8;
  const unsigned short* arow = wint + (long)plocal * I_DIM + kb;
  const unsigned short* brow = dA_bf + ((long)e * R_LORA + slot) * I_DIM + kb;
  f32x4 acc = {};
#pragma unroll 4
  for (int k = 0; k < 1024; k += 32)
    acc = MFMA_BF16(*(const sv8*)(arow + k), *(const sv8*)(brow + k), acc);
  const int orow = (lane >> 4) * 4;
  const long base = (long)blockIdx.y * P_TOT;
#pragma unroll
  for (int rg = 0; rg < 4; ++rg) {
    int pidx2 = grp * 16 + orow + rg;
    if (pidx2 < npairs) {
      int pr = lst[pidx2];
      vv[(base + pr) * R_LORA + slot] = acc[rg];
    }
  }
}

__global__ void reduce_v_kernel(const float* __restrict__ vv, float* __restrict__ vbuf) {
  long i = (long)blockIdx.x * 256 + threadIdx.x;
  float s = 0.f;
#pragma unroll
  for (int kc = 0; kc < 8; ++kc) s += vv[(long)kc * P_TOT * R_LORA + i];
  vbuf[i] = s;
}

// ---------------- fused epilogue: out = SC*(v'0@dB[e0].T + v'1@dB[e1].T) + p0 + p1
__global__ void ddmerge_kernel(const float* __restrict__ vbuf, const int* __restrict__ idxb,
                               const float* __restrict__ dB,   // [E,H,R] f32
                               const float* __restrict__ p0, const float* __restrict__ p1,
                               float* __restrict__ out) {
  const int t = blockIdx.y;
  const int h = blockIdx.x * 256 + threadIdx.x;
  const int e0 = idxb[t * 2 + 0], e1 = idxb[t * 2 + 1];
  const float4* v0p = (const float4*)(vbuf + (long)(t * 2 + 0) * R_LORA);
  const float4* v1p = (const float4*)(vbuf + (long)(t * 2 + 1) * R_LORA);
  const float4* b0 = (const float4*)(dB + ((long)e0 * H_DIM + h) * R_LORA);
  const float4* b1 = (const float4*)(dB + ((long)e1 * H_DIM + h) * R_LORA);
  float dd = 0.f;
#pragma unroll
  for (int qq = 0; qq < 4; ++qq) {
    float4 v0 = v0p[qq], x0 = b0[qq];
    float4 v1 = v1p[qq], x1 = b1[qq];
    dd += v0.x * x0.x + v0.y * x0.y + v0.z * x0.z + v0.w * x0.w;
    dd += v1.x * x1.x + v1.y * x1.y + v1.z * x1.z + v1.w * x1.w;
  }
  long i = (long)t * H_DIM + h;
  out[i] = SCALING * dd + p0[i] + p1[i];
}

// =======================================================================
extern "C" void kernel_launch(void* const* d_in, const int* in_sizes, int n_in,
                              void* d_out, int out_size, void* d_ws, size_t ws_size,
                              hipStream_t stream) {
  (void)in_sizes; (void)n_in; (void)out_size;
  const float* x        = (const float*)d_in[0];
  const float* gate_W   = (const float*)d_in[1];
  const float* up_W     = (const float*)d_in[2];
  const float* down_W   = (const float*)d_in[3];
  const float* router_W = (const float*)d_in[4];
  const float* gate_A   = (const float*)d_in[5];
  const float* gate_B   = (const float*)d_in[6];
  const float* up_A     = (const float*)d_in[7];
  const float* up_B     = (const float*)d_in[8];
  const float* down_A   = (const float*)d_in[9];
  const float* down_B   = (const float*)d_in[10];
  float* out = (float*)d_out;

  char* ws = (char*)d_ws;
  size_t off = 0;
  auto take = [&](size_t bytes) -> char* {
    char* p = ws + off;
    off += (bytes + 255) & ~(size_t)255;
    return p;
  };
  unsigned short* xf_bf  = (unsigned short*)take((size_t)T_TOK * H_DIM * 2);          // 16MB; -> vv/gB_bf/uB_bf after gemm1
  unsigned short* gW_bf  = (unsigned short*)take((size_t)I_DIM * H_DIM * 2);          // 32MB; -> dW_bf after gemm1
  unsigned short* uW_bf  = (unsigned short*)take((size_t)I_DIM * H_DIM * 2);          // 32MB
  unsigned short* dA_bf  = (unsigned short*)take((size_t)E_NUM * R_LORA * I_DIM * 2); // 2MB
  unsigned short* g_bf   = (unsigned short*)take((size_t)T_TOK * I_DIM * 2);          // 64MB; -> acc_bf
  unsigned short* u_bf   = (unsigned short*)take((size_t)T_TOK * I_DIM * 2);          // 64MB; -> f32 partials for gemm2
  float* wbuf  = (float*)take((size_t)P_TOT * 4);
  int*   idxb  = (int*)take((size_t)P_TOT * 4);
  float* ug    = (float*)take((size_t)P_TOT * R_LORA * 4);
  float* uu    = (float*)take((size_t)P_TOT * R_LORA * 4);
  float* vbuf  = (float*)take((size_t)P_TOT * R_LORA * 4);
  float* probs = (float*)take((size_t)T_TOK * E_NUM * 4);
  int*   lcnt  = (int*)take((size_t)E_NUM * NQ * 4);
  int*   lists = (int*)take((size_t)E_NUM * NQ * TQ * 4);
  // winter LAST: runtime-adaptive quarter batch (QB quarters resident at once)
  const size_t qwin = (size_t)PQ * I_DIM * 2;   // 32MB per quarter
  size_t fixed = off;
  int QB = (ws_size >= fixed + 4 * qwin) ? 4 : 1;
  unsigned short* winterQ = (unsigned short*)take(qwin * QB);

  // Aliases (stream-ordered reuse of dead buffers):
  unsigned short* dW_bf  = gW_bf;           // cast after gemm1 consumed gW_bf
  unsigned short* acc_bf = g_bf;            // acc(q) overwrites rows combine(q) read
  float* vg = (float*)winterQ;
  float* vu = (float*)(winterQ + (size_t)1 * 1024 * 1024 / 2);
  unsigned short* gA_bf = winterQ + (size_t)2 * 1024 * 1024 / 2;
  unsigned short* uA_bf = winterQ + (size_t)5 * 512 * 1024 / 2;
  // xf region (16MB) after gemm1: vv [0,4MB), gB_bf [4,8MB), uB_bf [8,12MB)
  float* vv = (float*)xf_bf;
  unsigned short* gB_bf = (unsigned short*)((char*)xf_bf + ((size_t)4 << 20));
  unsigned short* uB_bf = (unsigned short*)((char*)xf_bf + ((size_t)8 << 20));
  float* pbuf = (float*)u_bf;               // 64MB = 2 x f32 partial of gemm2 (u_bf dead)

  if (ws_size < off) return;  // clean absmax-fail signals ws too small

  // 1. stats + router (emits xf_bf) + aux
  zero_lcnt<<<1, 64, 0, stream>>>(lcnt);
  router_kernel<<<T_TOK / 4, 256, 0, stream>>>(x, router_W, wbuf, idxb, probs, lcnt, lists, xf_bf);
  aux_kernel<<<1, 64, 0, stream>>>(probs, lcnt, out + (size_t)T_TOK * H_DIM);

  // 2. LoRA-A casts (fused pair) + pair-GEMM (MFMA, k-chunked) + reduce
  cast2_f32_to_bf16<<<dim3((E_NUM * R_LORA * H_DIM / 4) / 256, 2), 256, 0, stream>>>(
      (const float4*)gate_A, (usv4*)gA_bf, (const float4*)up_A, (usv4*)uA_bf);
  lora_a_mfma_kernel<<<dim3(NQ * E_NUM * 16, 2), 256, 0, stream>>>(xf_bf, gA_bf, uA_bf, lists, lcnt, vg, vu);
  reduce_uguu_kernel<<<(P_TOT * R_LORA) / 256, 256, 0, stream>>>(vg, vu, ug, uu);

  // 3. big-weight casts (gate_W + up_W fused)
  cast2_f32_to_bf16<<<dim3((I_DIM * H_DIM / 4) / 256, 2), 256, 0, stream>>>(
      (const float4*)gate_W, (usv4*)gW_bf, (const float4*)up_W, (usv4*)uW_bf);
  cast_f32_to_bf16<<<(E_NUM * R_LORA * I_DIM / 4) / 256, 256, 0, stream>>>((const float4*)down_A, (usv4*)dA_bf);

  // 4. fused gate/up base GEMM — 256² 2-phase, z picks (gate, up)
  hipFuncSetAttribute(reinterpret_cast<const void*>(&gemm8p_t<false>),
                      hipFuncAttributeMaxDynamicSharedMemorySize, 131072);
  hipFuncSetAttribute(reinterpret_cast<const void*>(&gemm8p_t<true>),
                      hipFuncAttributeMaxDynamicSharedMemorySize, 131072);
  gemm8p_t<false><<<dim3(I_DIM / 256, T_TOK / 256, 2), 512, 131072, stream>>>(
      xf_bf, gW_bf, uW_bf, g_bf, u_bf, nullptr,
      H_DIM, H_DIM, H_DIM, I_DIM, 0, 0, 0);

  // 5. dead-buffer casts: down_W -> gW region; gate_B/up_B bf16-pack -> xf region
  cast_f32_to_bf16<<<(H_DIM * I_DIM / 4) / 256, 256, 0, stream>>>((const float4*)down_W, (usv4*)dW_bf);
  cast2_f32_to_bf16<<<dim3((E_NUM * I_DIM * R_LORA / 4) / 256, 2), 256, 0, stream>>>(
      (const float4*)gate_B, (usv4*)gB_bf, (const float4*)up_B, (usv4*)uB_bf);

  // 6. quarter-batched: SwiGLU+LoRA-B (weighted) -> acc -> k-chunked lora_v
  for (int q0 = 0; q0 < NQ; q0 += QB) {
    combine2_kernel<<<dim3(I_DIM / 256, E_NUM * 16, QB), 256, 0, stream>>>(
        g_bf, u_bf, gB_bf, uB_bf, ug, uu, wbuf, lists, lcnt, winterQ, q0);
    acc_kernel<<<dim3((TQ * (I_DIM / 8)) / 256, 1, QB), 256, 0, stream>>>(winterQ, acc_bf, q0);
    lorav_mfma_kernel<<<dim3(E_NUM * 16, 8, QB), 256, 0, stream>>>(winterQ, dA_bf, lists, lcnt, vv, q0);
  }
  reduce_v_kernel<<<(P_TOT * R_LORA) / 256, 256, 0, stream>>>(vv, vbuf);

  // 7. down GEMM — 2-phase split-K (z = K-half), f32 partials
  gemm8p_t<true><<<dim3(H_DIM / 256, T_TOK / 256, 2), 512, 131072, stream>>>(
      acc_bf, dW_bf, dW_bf, nullptr, nullptr, pbuf,
      I_DIM / 2, I_DIM, I_DIM, H_DIM, I_DIM / 2, I_DIM / 2, (long)T_TOK * H_DIM);

  // 8. fused epilogue: out = SC*dd + p0 + p1
  ddmerge_kernel<<<dim3(H_DIM / 256, T_TOK), 256, 0, stream>>>(
      vbuf, idxb, down_B, (const float*)pbuf,
      (const float*)(pbuf + (size_t)T_TOK * H_DIM), out);
}